// Round 1
// baseline (50.373 us; speedup 1.0000x reference)
//
#include <hip/hip_runtime.h>
#include <math.h>

// ---- problem constants ----
#define NCH   2048
#define SZ    14
#define NPOS  (SZ*SZ)        // 196
#define NQ    (NPOS/4)       // 49 float4 per channel plane
#define NSL   64             // channel slices
#define CPS   (NCH/NSL)      // 32 channels per slice
#define NWIN  917
#define NB    64
#define PN    7

// window tables (13 ratios)
__device__ const int g_rh[13]    = {4,3,5,6,5,7,8,6,10,7,9,7,10};
__device__ const int g_rw[13]    = {4,5,3,6,7,5,8,10,6,9,7,10,7};
__device__ const int g_wbase[14] = {0,121,241,361,442,522,602,651,696,741,789,837,877,917};

// -------- kernel 1: channel sum, partial per (batch, slice) --------
__global__ __launch_bounds__(64) void k_chansum(const float4* __restrict__ x,
                                                float4* __restrict__ part) {
  const int b  = blockIdx.x;
  const int sl = blockIdx.y;
  const int q  = threadIdx.x;
  if (q >= NQ) return;
  const float4* p = x + ((size_t)b * NCH + (size_t)sl * CPS) * NQ + q;
  float ax = 0.f, ay = 0.f, az = 0.f, aw = 0.f;
#pragma unroll 8
  for (int c = 0; c < CPS; ++c) {
    float4 v = p[(size_t)c * NQ];
    ax += v.x; ay += v.y; az += v.z; aw += v.w;
  }
  float4 o; o.x = ax; o.y = ay; o.z = az; o.w = aw;
  part[((size_t)b * NSL + sl) * NQ + q] = o;
}

// -------- kernel 2: windows + NMS, one block per batch --------
__global__ __launch_bounds__(256) void k_nms(const float* __restrict__ part,
                                             float* __restrict__ out) {
  const int b   = blockIdx.x;
  const int tid = threadIdx.x;

  __shared__ float s[NPOS];
  __shared__ float sc[NWIN];   // original scores
  __shared__ float wk[NWIN];   // working scores (suppressed -> -inf)
  __shared__ float bx1[NWIN], by1[NWIN], bx2[NWIN], by2[NWIN], bar[NWIN];
  __shared__ float rv[256];
  __shared__ int   ri[256];

  // reduce 64 partial slices -> s[196]
  if (tid < NPOS) {
    float acc = 0.f;
    const float* p = part + (size_t)b * NSL * NPOS + tid;
    for (int sl = 0; sl < NSL; ++sl) acc += p[sl * NPOS];
    s[tid] = acc;
  }
  __syncthreads();

  // window scores + coords
  for (int w = tid; w < NWIN; w += 256) {
    int r = 0;
    while (w >= g_wbase[r + 1]) ++r;
    const int l  = w - g_wbase[r];
    const int RH = g_rh[r], RW = g_rw[r];
    const int ww = SZ - RW + 1;
    const int xi = l / ww, yi = l % ww;
    float sum = 0.f;
    for (int i = 0; i < RH; ++i)
      for (int j = 0; j < RW; ++j)
        sum += s[(xi + i) * SZ + (yi + j)];
    const float score = sum / (float)(RH * RW);
    sc[w] = score; wk[w] = score;
    out[NB * PN * 2 + b * NWIN + w] = score;
    // coords exactly as reference: x2/y2 from UNclamped x1/y1, then clamp
    float x1 = (float)(xi * 32 - 1);
    float y1 = (float)(yi * 32 - 1);
    float x2 = x1 + (float)(RH * 32);
    float y2 = y1 + (float)(RW * 32);
    if (x1 < 0.f) x1 = 0.f;
    if (y1 < 0.f) y1 = 0.f;
    bx1[w] = x1; by1[w] = y1; bx2[w] = x2; by2[w] = y2;
    bar[w] = (x2 - x1 + 1.f) * (y2 - y1 + 1.f);
  }
  __syncthreads();

  const int gb[4] = {0, 361, 602, 917};
  const int nl[3] = {2, 3, 2};
  int outpos = 0;
  for (int g = 0; g < 3; ++g) {
    const int lo = gb[g], hi = gb[g + 1];
    for (int st = 0; st < nl[g]; ++st) {
      // block argmax over [lo,hi), first-occurrence tie-break (jnp.argmax)
      float bv = -INFINITY; int bi = -1;
      for (int j = lo + tid; j < hi; j += 256) {
        float v = wk[j];
        if (v > bv) { bv = v; bi = j; }   // strict > keeps smallest j in stride
      }
      rv[tid] = bv; ri[tid] = bi;
      __syncthreads();
      for (int off = 128; off > 0; off >>= 1) {
        if (tid < off) {
          const float v2 = rv[tid + off]; const int i2 = ri[tid + off];
          const float v1 = rv[tid];       const int i1 = ri[tid];
          const bool take = (i2 >= 0) &&
                            (i1 < 0 || v2 > v1 || (v2 == v1 && i2 < i1));
          if (take) { rv[tid] = v2; ri[tid] = i2; }
        }
        __syncthreads();
      }
      const int i = ri[0];
      if (tid == 0) {
        out[b * PN + outpos]          = (float)i;   // index as float
        out[NB * PN + b * PN + outpos] = sc[i];     // original score
      }
      // suppression pass (fp32 IoU identical to reference arithmetic)
      const float X1 = bx1[i], Y1 = by1[i], X2 = bx2[i], Y2 = by2[i], AR = bar[i];
      for (int j = lo + tid; j < hi; j += 256) {
        const float ix1 = fmaxf(bx1[j], X1);
        const float iy1 = fmaxf(by1[j], Y1);
        const float ix2 = fminf(bx2[j], X2);
        const float iy2 = fminf(by2[j], Y2);
        const float lw = ix2 - ix1 + 1.f;
        const float lh = iy2 - iy1 + 1.f;
        const float inter = (lw < 0.f || lh < 0.f) ? 0.f : lw * lh;
        const float iou = inter / (bar[j] + AR - inter);
        if (iou > 0.25f || j == i) wk[j] = -INFINITY;
      }
      __syncthreads();
      ++outpos;
    }
  }
}

extern "C" void kernel_launch(void* const* d_in, const int* in_sizes, int n_in,
                              void* d_out, int out_size, void* d_ws, size_t ws_size,
                              hipStream_t stream) {
  const float4* x = (const float4*)d_in[0];
  float* out = (float*)d_out;
  float4* part = (float4*)d_ws;   // 64*64*49 float4 = 3.2 MB

  dim3 g1(NB, NSL);
  k_chansum<<<g1, 64, 0, stream>>>(x, part);
  k_nms<<<NB, 256, 0, stream>>>((const float*)d_ws, out);
}

// Round 2
// 41.875 us; speedup vs baseline: 1.2029x; 1.2029x over previous
//
#include <hip/hip_runtime.h>
#include <math.h>

// ---- problem constants ----
#define NCH   2048
#define SZ    14
#define NPOS  (SZ*SZ)        // 196
#define NQ    (NPOS/4)       // 49 float4 per channel plane
#define NSL   64             // channel slices
#define CPS   (NCH/NSL)      // 32 channels per slice
#define NWIN  917
#define NB    64
#define PN    7
#define KPER  6              // ceil(361/64) strided candidates per lane

// window tables (13 ratios)
__device__ const int g_rh[13]    = {4,3,5,6,5,7,8,6,10,7,9,7,10};
__device__ const int g_rw[13]    = {4,5,3,6,7,5,8,10,6,9,7,10,7};
__device__ const int g_wbase[14] = {0,121,241,361,442,522,602,651,696,741,789,837,877,917};

// -------- kernel 1: channel sum, partial per (batch, slice) --------
__global__ __launch_bounds__(256) void k_chansum(const float4* __restrict__ x,
                                                 float4* __restrict__ part) {
  const int b  = blockIdx.x;
  const int sl = blockIdx.y * 4 + (threadIdx.x >> 6);
  const int q  = threadIdx.x & 63;
  if (q >= NQ) return;
  const float4* p = x + ((size_t)b * NCH + (size_t)sl * CPS) * NQ + q;
  float ax = 0.f, ay = 0.f, az = 0.f, aw = 0.f;
#pragma unroll 8
  for (int c = 0; c < CPS; ++c) {
    float4 v = p[(size_t)c * NQ];
    ax += v.x; ay += v.y; az += v.z; aw += v.w;
  }
  float4 o; o.x = ax; o.y = ay; o.z = az; o.w = aw;
  part[((size_t)b * NSL + sl) * NQ + q] = o;
}

// -------- kernel 2: windows + wave-parallel NMS, one block per batch --------
__global__ __launch_bounds__(256) void k_nms(const float* __restrict__ part,
                                             float* __restrict__ out) {
  const int b    = blockIdx.x;
  const int tid  = threadIdx.x;
  const int lane = tid & 63;
  const int wave = tid >> 6;

  __shared__ float s[NPOS];
  __shared__ float sc[NWIN];   // original scores (read-only after barrier)
  __shared__ float bx1[NWIN], by1[NWIN], bx2[NWIN], by2[NWIN], bar[NWIN];

  // reduce 64 partial slices -> s[196]
  if (tid < NPOS) {
    float acc = 0.f;
    const float* p = part + (size_t)b * NSL * NPOS + tid;
#pragma unroll 8
    for (int sl = 0; sl < NSL; ++sl) acc += p[sl * NPOS];
    s[tid] = acc;
  }
  __syncthreads();

  // window scores + coords (coords exactly as reference: clamp AFTER x2/y2)
  for (int w = tid; w < NWIN; w += 256) {
    int r = 0;
    while (w >= g_wbase[r + 1]) ++r;
    const int l  = w - g_wbase[r];
    const int RH = g_rh[r], RW = g_rw[r];
    const int ww = SZ - RW + 1;
    const int xi = l / ww, yi = l % ww;
    float sum = 0.f;
    for (int i = 0; i < RH; ++i)
      for (int j = 0; j < RW; ++j)
        sum += s[(xi + i) * SZ + (yi + j)];
    const float score = sum / (float)(RH * RW);
    sc[w] = score;
    out[NB * PN * 2 + b * NWIN + w] = score;
    float x1 = (float)(xi * 32 - 1);
    float y1 = (float)(yi * 32 - 1);
    float x2 = x1 + (float)(RH * 32);
    float y2 = y1 + (float)(RW * 32);
    if (x1 < 0.f) x1 = 0.f;
    if (y1 < 0.f) y1 = 0.f;
    bx1[w] = x1; by1[w] = y1; bx2[w] = x2; by2[w] = y2;
    bar[w] = (x2 - x1 + 1.f) * (y2 - y1 + 1.f);
  }
  __syncthreads();

  // one wave per NMS group, fully wave-synchronous (no barriers)
  if (wave < 3) {
    const int glo[3] = {0, 361, 602};
    const int ghi[3] = {361, 602, 917};
    const int gns[3] = {2, 3, 2};
    const int gob[3] = {0, 2, 5};
    const int lo = glo[wave], hi = ghi[wave];
    const int nsel = gns[wave], obase = gob[wave];

    float wk[KPER], X1[KPER], Y1[KPER], X2[KPER], Y2[KPER], AR[KPER];
#pragma unroll
    for (int k = 0; k < KPER; ++k) {
      const int j = lo + lane + k * 64;
      const bool v = j < hi;
      const int jj = v ? j : lo;
      wk[k] = v ? sc[jj] : -INFINITY;
      X1[k] = bx1[jj]; Y1[k] = by1[jj];
      X2[k] = bx2[jj]; Y2[k] = by2[jj]; AR[k] = bar[jj];
    }

    for (int st = 0; st < nsel; ++st) {
      // local argmax (k ascending => j ascending; strict > keeps smallest j)
      float bv = -INFINITY; int bj = 0x7fffffff;
#pragma unroll
      for (int k = 0; k < KPER; ++k) {
        const int j = lo + lane + k * 64;
        if (wk[k] > bv) { bv = wk[k]; bj = j; }
      }
      // wave argmax, first-occurrence tie-break (smaller j on equal value)
      for (int off = 32; off > 0; off >>= 1) {
        const float ov = __shfl_xor(bv, off);
        const int   oj = __shfl_xor(bj, off);
        if (ov > bv || (ov == bv && oj < bj)) { bv = ov; bj = oj; }
      }
      // bj uniform across the wave now
      const float sx1 = bx1[bj], sy1 = by1[bj];
      const float sx2 = bx2[bj], sy2 = by2[bj], sar = bar[bj];
      if (lane == 0) {
        out[b * PN + obase + st]          = (float)bj;
        out[NB * PN + b * PN + obase + st] = sc[bj];
      }
      // suppression in registers (fp32 IoU identical to reference arithmetic)
#pragma unroll
      for (int k = 0; k < KPER; ++k) {
        const int j = lo + lane + k * 64;
        const float ix1 = fmaxf(X1[k], sx1);
        const float iy1 = fmaxf(Y1[k], sy1);
        const float ix2 = fminf(X2[k], sx2);
        const float iy2 = fminf(Y2[k], sy2);
        const float lw = ix2 - ix1 + 1.f;
        const float lh = iy2 - iy1 + 1.f;
        const float inter = (lw < 0.f || lh < 0.f) ? 0.f : lw * lh;
        const float iou = inter / (AR[k] + sar - inter);
        if (iou > 0.25f || j == bj) wk[k] = -INFINITY;
      }
    }
  }
}

extern "C" void kernel_launch(void* const* d_in, const int* in_sizes, int n_in,
                              void* d_out, int out_size, void* d_ws, size_t ws_size,
                              hipStream_t stream) {
  const float4* x = (const float4*)d_in[0];
  float* out = (float*)d_out;
  float4* part = (float4*)d_ws;   // 64*64*49 float4 = 3.2 MB

  dim3 g1(NB, NSL / 4);
  k_chansum<<<g1, 256, 0, stream>>>(x, part);
  k_nms<<<NB, 256, 0, stream>>>((const float*)d_ws, out);
}